// Round 4
// baseline (457.658 us; speedup 1.0000x reference)
//
#include <hip/hip_runtime.h>

#define N_NODES 50000
#define N_EDGES 600000
#define CH 128
#define NUM_GRAPHS 512
#define OUT_CH 64

typedef unsigned int uint32;

// pack two fp32 -> bf16x2 (RNE), lo = first channel
__device__ __forceinline__ uint32 bfpack(float a, float b) {
    uint32 ua = __builtin_bit_cast(uint32, a);
    uint32 ub = __builtin_bit_cast(uint32, b);
    ua = (ua + 0x7fffu + ((ua >> 16) & 1u)) >> 16;
    ub = (ub + 0x7fffu + ((ub >> 16) & 1u)) >> 16;
    return (ub << 16) | ua;
}
__device__ __forceinline__ float bf_lo(uint32 v) {
    return __builtin_bit_cast(float, v << 16);
}
__device__ __forceinline__ float bf_hi(uint32 v) {
    return __builtin_bit_cast(float, v & 0xffff0000u);
}

// ---------------- CSR build (counting sort by dst) ----------------

__global__ void k_count(const int* __restrict__ dst, int* __restrict__ deg) {
    int e = blockIdx.x * 256 + threadIdx.x;
    if (e < N_EDGES) atomicAdd(&deg[dst[e]], 1);
}

__global__ void k_scan1(const int* __restrict__ deg, int* __restrict__ off,
                        int* __restrict__ bsum) {
    __shared__ int sd[256];
    int tid = threadIdx.x;
    int base = blockIdx.x * 1024 + tid * 4;
    int v0 = (base + 0 < N_NODES) ? deg[base + 0] : 0;
    int v1 = (base + 1 < N_NODES) ? deg[base + 1] : 0;
    int v2 = (base + 2 < N_NODES) ? deg[base + 2] : 0;
    int v3 = (base + 3 < N_NODES) ? deg[base + 3] : 0;
    int tsum = v0 + v1 + v2 + v3;
    sd[tid] = tsum;
    __syncthreads();
    for (int d = 1; d < 256; d <<= 1) {
        int t = (tid >= d) ? sd[tid - d] : 0;
        __syncthreads();
        sd[tid] += t;
        __syncthreads();
    }
    int excl = sd[tid] - tsum;
    if (base + 0 < N_NODES) off[base + 0] = excl;
    if (base + 1 < N_NODES) off[base + 1] = excl + v0;
    if (base + 2 < N_NODES) off[base + 2] = excl + v0 + v1;
    if (base + 3 < N_NODES) off[base + 3] = excl + v0 + v1 + v2;
    if (tid == 255) bsum[blockIdx.x] = sd[255];
}

__global__ void k_scan2(const int* __restrict__ bsum, int* __restrict__ bsum2, int nblk) {
    __shared__ int sd[64];
    int tid = threadIdx.x;
    int v = (tid < nblk) ? bsum[tid] : 0;
    sd[tid] = v;
    __syncthreads();
    for (int d = 1; d < 64; d <<= 1) {
        int t = (tid >= d) ? sd[tid - d] : 0;
        __syncthreads();
        sd[tid] += t;
        __syncthreads();
    }
    bsum2[tid] = sd[tid] - v;
}

// also computes dinv (fused)
__global__ void k_scan3(int* __restrict__ off, int* __restrict__ cur,
                        const int* __restrict__ bsum2, const int* __restrict__ deg,
                        float* __restrict__ dinv) {
    int base = blockIdx.x * 1024 + threadIdx.x * 4;
    int add = bsum2[blockIdx.x];
    #pragma unroll
    for (int j = 0; j < 4; ++j) {
        int i = base + j;
        if (i < N_NODES) {
            int v = off[i] + add;
            off[i] = v;
            cur[i] = v;
            dinv[i] = rsqrtf((float)(deg[i] + 1));
        }
    }
}

__global__ void k_fill(const int* __restrict__ src, const int* __restrict__ dst,
                       int* __restrict__ cur, int* __restrict__ srcs) {
    int e = blockIdx.x * 256 + threadIdx.x;
    if (e < N_EDGES) {
        int s = src[e];
        int p = atomicAdd(&cur[dst[e]], 1);
        srcs[p] = s;
    }
}

// ---------------- dense GEMM v3: out[N,128] = A[N,128] @ W[128,128] ----------------
// 128 threads (2 waves), block tile 128 rows x 128 cols, thread tile 8r x 16c.
// A read from LDS as b128 along k (xs stride 36 -> conflict-free), W b128 broadcast.
// Writes fp32 out + pre-scaled bf16 copy outb[row] = bf16(out*dinv[row]).
__global__ __launch_bounds__(128, 2) void k_gemm(const float* __restrict__ A,
                                                 const float* __restrict__ W,
                                                 const float* __restrict__ dinv,
                                                 float* __restrict__ out,
                                                 uint32* __restrict__ outb) {
    __shared__ float xs[128][36];   // [row][k], stride 36 (== 4 mod 32)
    __shared__ float ws[32][128];   // [k][col]
    int tid = threadIdx.x;
    int cg = tid & 7;     // cols cg*4 + j*32
    int rg = tid >> 3;    // rows rg + 16*i, i=0..7
    int row0 = blockIdx.x * 128;
    float acc[8][16];
    #pragma unroll
    for (int i = 0; i < 8; ++i)
        #pragma unroll
        for (int j = 0; j < 16; ++j) acc[i][j] = 0.f;

    for (int kc = 0; kc < CH; kc += 32) {
        #pragma unroll
        for (int it = 0; it < 8; ++it) {      // x: 128 rows x 32 k = 1024 float4
            int idx = it * 128 + tid;
            int r = idx >> 3;
            int k4 = (idx & 7) << 2;
            float4 v = make_float4(0.f, 0.f, 0.f, 0.f);
            int gr = row0 + r;
            if (gr < N_NODES) v = *(const float4*)&A[gr * CH + kc + k4];
            *(float4*)&xs[r][k4] = v;
        }
        #pragma unroll
        for (int it = 0; it < 8; ++it) {      // W: 32 k x 128 c = 1024 float4
            int idx = it * 128 + tid;
            int k = idx >> 5;
            int c4 = (idx & 31) << 2;
            *(float4*)&ws[k][c4] = *(const float4*)&W[(kc + k) * CH + c4];
        }
        __syncthreads();
        #pragma unroll
        for (int kt = 0; kt < 32; kt += 4) {
            float4 a[8];
            #pragma unroll
            for (int i = 0; i < 8; ++i) a[i] = *(float4*)&xs[rg + 16 * i][kt];
            #pragma unroll
            for (int dk = 0; dk < 4; ++dk) {
                float4 w0 = *(float4*)&ws[kt + dk][cg * 4 + 0];
                float4 w1 = *(float4*)&ws[kt + dk][cg * 4 + 32];
                float4 w2 = *(float4*)&ws[kt + dk][cg * 4 + 64];
                float4 w3 = *(float4*)&ws[kt + dk][cg * 4 + 96];
                #pragma unroll
                for (int i = 0; i < 8; ++i) {
                    float av = (dk == 0) ? a[i].x : (dk == 1) ? a[i].y
                             : (dk == 2) ? a[i].z : a[i].w;
                    acc[i][0]  += av * w0.x; acc[i][1]  += av * w0.y;
                    acc[i][2]  += av * w0.z; acc[i][3]  += av * w0.w;
                    acc[i][4]  += av * w1.x; acc[i][5]  += av * w1.y;
                    acc[i][6]  += av * w1.z; acc[i][7]  += av * w1.w;
                    acc[i][8]  += av * w2.x; acc[i][9]  += av * w2.y;
                    acc[i][10] += av * w2.z; acc[i][11] += av * w2.w;
                    acc[i][12] += av * w3.x; acc[i][13] += av * w3.y;
                    acc[i][14] += av * w3.z; acc[i][15] += av * w3.w;
                }
            }
        }
        __syncthreads();
    }
    #pragma unroll
    for (int i = 0; i < 8; ++i) {
        int gr = row0 + rg + 16 * i;
        if (gr < N_NODES) {
            float sc = dinv[gr];
            #pragma unroll
            for (int j = 0; j < 4; ++j) {
                float4 v = make_float4(acc[i][j * 4 + 0], acc[i][j * 4 + 1],
                                       acc[i][j * 4 + 2], acc[i][j * 4 + 3]);
                *(float4*)&out[gr * CH + cg * 4 + j * 32] = v;
                uint32 p0 = bfpack(v.x * sc, v.y * sc);
                uint32 p1 = bfpack(v.z * sc, v.w * sc);
                uint2 pp = make_uint2(p0, p1);
                *(uint2*)&outb[gr * 64 + cg * 2 + j * 16] = pp;
            }
        }
    }
}

// ---------------- aggregation v4: bf16 gathers of pre-scaled rows ----------------
// out[d] = relu(dinv[d]*(sum_e hb[s] + dinv[d]*h[d]) + b), hb pre-scaled by dinv[s].
// One wave64 per node; lane = bf16x2 channel pair (4B) -> 256B/edge, coalesced.
__global__ __launch_bounds__(256) void k_agg(const float* __restrict__ h,
                                             const uint32* __restrict__ hb,
                                             const float* __restrict__ dinv,
                                             const int* __restrict__ off,
                                             const int* __restrict__ deg,
                                             const int* __restrict__ srcs,
                                             const float* __restrict__ bias,
                                             float* __restrict__ out) {
    int node = __builtin_amdgcn_readfirstlane(blockIdx.x * 4 + (threadIdx.x >> 6));
    int lane = threadIdx.x & 63;

    float dn = dinv[node];
    float2 hs = ((const float2*)h)[node * 64 + lane];
    float ax = hs.x * dn, ay = hs.y * dn;   // exact self-loop term (dinv*h)

    int start = off[node];
    int cnt = deg[node];
    int last = start + cnt - 1;
    for (int j = 0; j < cnt; j += 8) {
        int i0 = start + j;
        int i1 = min(i0 + 1, last);
        int i2 = min(i0 + 2, last);
        int i3 = min(i0 + 3, last);
        int i4 = min(i0 + 4, last);
        int i5 = min(i0 + 5, last);
        int i6 = min(i0 + 6, last);
        int i7 = min(i0 + 7, last);
        int s0 = srcs[i0], s1 = srcs[i1], s2 = srcs[i2], s3 = srcs[i3];
        int s4 = srcs[i4], s5 = srcs[i5], s6 = srcs[i6], s7 = srcs[i7];
        uint32 v0 = hb[s0 * 64 + lane];
        uint32 v1 = hb[s1 * 64 + lane];
        uint32 v2 = hb[s2 * 64 + lane];
        uint32 v3 = hb[s3 * 64 + lane];
        uint32 v4 = hb[s4 * 64 + lane];
        uint32 v5 = hb[s5 * 64 + lane];
        uint32 v6 = hb[s6 * 64 + lane];
        uint32 v7 = hb[s7 * 64 + lane];
        int rem = cnt - j;
        v1 = (rem > 1) ? v1 : 0u;
        v2 = (rem > 2) ? v2 : 0u;
        v3 = (rem > 3) ? v3 : 0u;
        v4 = (rem > 4) ? v4 : 0u;
        v5 = (rem > 5) ? v5 : 0u;
        v6 = (rem > 6) ? v6 : 0u;
        v7 = (rem > 7) ? v7 : 0u;
        ax += bf_lo(v0); ay += bf_hi(v0);
        ax += bf_lo(v1); ay += bf_hi(v1);
        ax += bf_lo(v2); ay += bf_hi(v2);
        ax += bf_lo(v3); ay += bf_hi(v3);
        ax += bf_lo(v4); ay += bf_hi(v4);
        ax += bf_lo(v5); ay += bf_hi(v5);
        ax += bf_lo(v6); ay += bf_hi(v6);
        ax += bf_lo(v7); ay += bf_hi(v7);
    }
    float2 b = ((const float2*)bias)[lane];
    ax = fmaxf(ax * dn + b.x, 0.f);
    ay = fmaxf(ay * dn + b.y, 0.f);
    ((float2*)out)[node * 64 + lane] = make_float2(ax, ay);
}

// ---------------- fused mean-pool + linear (batch is sorted) ----------------
__global__ void k_pool_linear(const float* __restrict__ h, const int* __restrict__ batch,
                              const float* __restrict__ Wl, const float* __restrict__ bl,
                              float* __restrict__ out) {
    __shared__ int sb[2];
    __shared__ float xr[CH];
    int g = blockIdx.x;
    if (threadIdx.x < 2) {
        int target = g + (int)threadIdx.x;
        int lo = 0, hi = N_NODES;
        while (lo < hi) {
            int mid = (lo + hi) >> 1;
            if (batch[mid] < target) lo = mid + 1; else hi = mid;
        }
        sb[threadIdx.x] = lo;
    }
    __syncthreads();
    int lo = sb[0], hi = sb[1];
    int c = threadIdx.x;  // 128 threads
    float acc = 0.f;
    for (int i = lo; i < hi; ++i) acc += h[i * CH + c];
    float cnt = (float)((hi - lo) > 0 ? (hi - lo) : 1);
    xr[c] = acc / cnt;
    __syncthreads();
    if (c < OUT_CH) {
        float o = bl[c];
        #pragma unroll 8
        for (int k = 0; k < CH; ++k) o += xr[k] * Wl[k * OUT_CH + c];
        out[g * OUT_CH + c] = o;
    }
}

extern "C" void kernel_launch(void* const* d_in, const int* in_sizes, int n_in,
                              void* d_out, int out_size, void* d_ws, size_t ws_size,
                              hipStream_t stream) {
    const float* x    = (const float*)d_in[0];
    const float* W1   = (const float*)d_in[1];
    const float* b1   = (const float*)d_in[2];
    const float* W2   = (const float*)d_in[3];
    const float* b2   = (const float*)d_in[4];
    const float* Wlin = (const float*)d_in[5];
    const float* blin = (const float*)d_in[6];
    const int* ei     = (const int*)d_in[7];
    const int* batch  = (const int*)d_in[8];
    const int* esrc = ei;
    const int* edst = ei + N_EDGES;
    float* out = (float*)d_out;

    char* w = (char*)d_ws;
    size_t o = 0;
    float* t1     = (float*)(w + o);  o += (size_t)N_NODES * CH * 4;  // gemm out (reused for layer2)
    float* h2     = (float*)(w + o);  o += (size_t)N_NODES * CH * 4;  // agg out (reused for layer2)
    uint32* hb    = (uint32*)(w + o); o += (size_t)N_NODES * 64 * 4;  // bf16 pre-scaled copy
    float* dinv   = (float*)(w + o);  o += 200704;
    int* deg      = (int*)(w + o);    o += 200704;
    int* off      = (int*)(w + o);    o += 200704;
    int* cur      = (int*)(w + o);    o += 200704;
    int* srcs     = (int*)(w + o);    o += (size_t)N_EDGES * 4;
    int* bsum     = (int*)(w + o);    o += 256;
    int* bsum2    = (int*)(w + o);    o += 256;
    (void)ws_size; (void)in_sizes; (void)n_in; (void)out_size;

    hipMemsetAsync(deg, 0, N_NODES * sizeof(int), stream);

    dim3 b256(256);
    dim3 gE((N_EDGES + 255) / 256);
    k_count<<<gE, b256, 0, stream>>>(edst, deg);
    k_scan1<<<dim3(49), b256, 0, stream>>>(deg, off, bsum);
    k_scan2<<<dim3(1), dim3(64), 0, stream>>>(bsum, bsum2, 49);
    k_scan3<<<dim3(49), b256, 0, stream>>>(off, cur, bsum2, deg, dinv);
    k_fill<<<gE, b256, 0, stream>>>(esrc, edst, cur, srcs);

    dim3 gG((N_NODES + 127) / 128);   // 391 blocks, 128 threads
    dim3 gA(N_NODES / 4);             // 12500 blocks, one wave64 per node
    k_gemm<<<gG, dim3(128), 0, stream>>>(x, W1, dinv, t1, hb);
    k_agg<<<gA, b256, 0, stream>>>(t1, hb, dinv, off, deg, srcs, b1, h2);
    k_gemm<<<gG, dim3(128), 0, stream>>>(h2, W2, dinv, t1, hb);
    k_agg<<<gA, b256, 0, stream>>>(t1, hb, dinv, off, deg, srcs, b2, h2);
    k_pool_linear<<<dim3(NUM_GRAPHS), dim3(128), 0, stream>>>(h2, batch, Wlin, blin, out);
}

// Round 5
// 273.187 us; speedup vs baseline: 1.6753x; 1.6753x over previous
//
#include <hip/hip_runtime.h>

#define N_NODES 50000
#define N_EDGES 600000
#define CH 128
#define NUM_GRAPHS 512
#define OUT_CH 64
// padded bucket stride (max degree safety: Poisson(12), P(>=64) ~ 0)
#define DSH 6
#define DSTRIDE 64

typedef unsigned int uint32;

// pack two fp32 -> bf16x2 (RNE), lo = first channel
__device__ __forceinline__ uint32 bfpack(float a, float b) {
    uint32 ua = __builtin_bit_cast(uint32, a);
    uint32 ub = __builtin_bit_cast(uint32, b);
    ua = (ua + 0x7fffu + ((ua >> 16) & 1u)) >> 16;
    ub = (ub + 0x7fffu + ((ub >> 16) & 1u)) >> 16;
    return (ub << 16) | ua;
}
__device__ __forceinline__ float bf_lo(uint32 v) {
    return __builtin_bit_cast(float, v << 16);
}
__device__ __forceinline__ float bf_hi(uint32 v) {
    return __builtin_bit_cast(float, v & 0xffff0000u);
}

// ---------------- padded-CSR build: one pass, no scan ----------------
__global__ void k_fill_pad(const int* __restrict__ src, const int* __restrict__ dst,
                           int* __restrict__ cur, int* __restrict__ srcs) {
    int e = blockIdx.x * 256 + threadIdx.x;
    if (e < N_EDGES) {
        int s = src[e];
        int d = dst[e];
        int p = atomicAdd(&cur[d], 1);
        srcs[(d << DSH) + p] = s;
    }
}

__global__ void k_dinv(const int* __restrict__ cur, float* __restrict__ dinv) {
    int i = blockIdx.x * 256 + threadIdx.x;
    if (i < N_NODES) dinv[i] = rsqrtf((float)(cur[i] + 1));  // +1 self-loop
}

// ---------------- dense GEMM v5: outb[N,128](bf16) = bf16(dinv*(A @ W)) ----------------
// 256 threads, block tile 128 rows x 128 cols, thread tile 4r x 16c (acc=64 regs).
// W resides fully in LDS (64 KB, staged once, one barrier). A read directly from
// global: each row belongs to exactly one wave -> 512B contiguous per row, L1/L2-hot.
// Per 4-k step: 4 global b128 + 16 LDS b128 -> 256 FMAs. Barrier-free K-loop.
__global__ __launch_bounds__(256, 2) void k_gemm(const float* __restrict__ A,
                                                 const float* __restrict__ W,
                                                 const float* __restrict__ dinv,
                                                 uint32* __restrict__ outb) {
    __shared__ float ws[CH][CH];   // 64 KB, [k][col]
    int tid = threadIdx.x;
    int cg = tid & 7;    // cols cg*4 + q*32
    int rg = tid >> 3;   // rows rg*4 + rr
    int row0 = blockIdx.x * 128;

    #pragma unroll
    for (int it = 0; it < 16; ++it) {          // 4096 float4 total
        int idx = it * 256 + tid;
        int k = idx >> 5;
        int c4 = (idx & 31) << 2;
        *(float4*)&ws[k][c4] = *(const float4*)&W[k * CH + c4];
    }
    __syncthreads();

    // clamped row pointers (duplicate compute for tail rows; stores guarded)
    const float* ap[4];
    #pragma unroll
    for (int rr = 0; rr < 4; ++rr) {
        int gr = row0 + rg * 4 + rr;
        ap[rr] = &A[(size_t)min(gr, N_NODES - 1) * CH];
    }

    float acc[4][16];
    #pragma unroll
    for (int i = 0; i < 4; ++i)
        #pragma unroll
        for (int j = 0; j < 16; ++j) acc[i][j] = 0.f;

    for (int kt = 0; kt < CH; kt += 4) {
        float4 a0 = *(const float4*)(ap[0] + kt);
        float4 a1 = *(const float4*)(ap[1] + kt);
        float4 a2 = *(const float4*)(ap[2] + kt);
        float4 a3 = *(const float4*)(ap[3] + kt);
        #pragma unroll
        for (int dk = 0; dk < 4; ++dk) {
            float4 w0 = *(float4*)&ws[kt + dk][cg * 4 + 0];
            float4 w1 = *(float4*)&ws[kt + dk][cg * 4 + 32];
            float4 w2 = *(float4*)&ws[kt + dk][cg * 4 + 64];
            float4 w3 = *(float4*)&ws[kt + dk][cg * 4 + 96];
            float v0 = (dk == 0) ? a0.x : (dk == 1) ? a0.y : (dk == 2) ? a0.z : a0.w;
            float v1 = (dk == 0) ? a1.x : (dk == 1) ? a1.y : (dk == 2) ? a1.z : a1.w;
            float v2 = (dk == 0) ? a2.x : (dk == 1) ? a2.y : (dk == 2) ? a2.z : a2.w;
            float v3 = (dk == 0) ? a3.x : (dk == 1) ? a3.y : (dk == 2) ? a3.z : a3.w;
            acc[0][0]  += v0 * w0.x; acc[0][1]  += v0 * w0.y;
            acc[0][2]  += v0 * w0.z; acc[0][3]  += v0 * w0.w;
            acc[0][4]  += v0 * w1.x; acc[0][5]  += v0 * w1.y;
            acc[0][6]  += v0 * w1.z; acc[0][7]  += v0 * w1.w;
            acc[0][8]  += v0 * w2.x; acc[0][9]  += v0 * w2.y;
            acc[0][10] += v0 * w2.z; acc[0][11] += v0 * w2.w;
            acc[0][12] += v0 * w3.x; acc[0][13] += v0 * w3.y;
            acc[0][14] += v0 * w3.z; acc[0][15] += v0 * w3.w;
            acc[1][0]  += v1 * w0.x; acc[1][1]  += v1 * w0.y;
            acc[1][2]  += v1 * w0.z; acc[1][3]  += v1 * w0.w;
            acc[1][4]  += v1 * w1.x; acc[1][5]  += v1 * w1.y;
            acc[1][6]  += v1 * w1.z; acc[1][7]  += v1 * w1.w;
            acc[1][8]  += v1 * w2.x; acc[1][9]  += v1 * w2.y;
            acc[1][10] += v1 * w2.z; acc[1][11] += v1 * w2.w;
            acc[1][12] += v1 * w3.x; acc[1][13] += v1 * w3.y;
            acc[1][14] += v1 * w3.z; acc[1][15] += v1 * w3.w;
            acc[2][0]  += v2 * w0.x; acc[2][1]  += v2 * w0.y;
            acc[2][2]  += v2 * w0.z; acc[2][3]  += v2 * w0.w;
            acc[2][4]  += v2 * w1.x; acc[2][5]  += v2 * w1.y;
            acc[2][6]  += v2 * w1.z; acc[2][7]  += v2 * w1.w;
            acc[2][8]  += v2 * w2.x; acc[2][9]  += v2 * w2.y;
            acc[2][10] += v2 * w2.z; acc[2][11] += v2 * w2.w;
            acc[2][12] += v2 * w3.x; acc[2][13] += v2 * w3.y;
            acc[2][14] += v2 * w3.z; acc[2][15] += v2 * w3.w;
            acc[3][0]  += v3 * w0.x; acc[3][1]  += v3 * w0.y;
            acc[3][2]  += v3 * w0.z; acc[3][3]  += v3 * w0.w;
            acc[3][4]  += v3 * w1.x; acc[3][5]  += v3 * w1.y;
            acc[3][6]  += v3 * w1.z; acc[3][7]  += v3 * w1.w;
            acc[3][8]  += v3 * w2.x; acc[3][9]  += v3 * w2.y;
            acc[3][10] += v3 * w2.z; acc[3][11] += v3 * w2.w;
            acc[3][12] += v3 * w3.x; acc[3][13] += v3 * w3.y;
            acc[3][14] += v3 * w3.z; acc[3][15] += v3 * w3.w;
        }
    }

    #pragma unroll
    for (int rr = 0; rr < 4; ++rr) {
        int gr = row0 + rg * 4 + rr;
        if (gr < N_NODES) {
            float sc = dinv[gr];
            #pragma unroll
            for (int q = 0; q < 4; ++q) {
                uint32 p0 = bfpack(acc[rr][q * 4 + 0] * sc, acc[rr][q * 4 + 1] * sc);
                uint32 p1 = bfpack(acc[rr][q * 4 + 2] * sc, acc[rr][q * 4 + 3] * sc);
                *(uint2*)&outb[gr * 64 + cg * 2 + q * 16] = make_uint2(p0, p1);
            }
        }
    }
}

// ---------------- aggregation v5: padded buckets, pure bf16 gathers ----------------
// out[d] = relu(dinv[d]*(sum_{s in bucket+self} bf16(dinv[s]*h[s])) + b)
// One wave64 per node; lane = bf16x2 channel pair (4B) -> 256B/edge, coalesced.
__global__ __launch_bounds__(256) void k_agg(const uint32* __restrict__ hb,
                                             const float* __restrict__ dinv,
                                             const int* __restrict__ cnt_arr,
                                             const int* __restrict__ srcs,
                                             const float* __restrict__ bias,
                                             float* __restrict__ out) {
    int node = __builtin_amdgcn_readfirstlane(blockIdx.x * 4 + (threadIdx.x >> 6));
    int lane = threadIdx.x & 63;

    float dn = dinv[node];
    uint32 vs = hb[node * 64 + lane];       // self-loop: bf16(dinv[n]*h[n])
    float ax = bf_lo(vs), ay = bf_hi(vs);

    int start = node << DSH;
    int cnt = cnt_arr[node];
    int last = start + cnt - 1;
    for (int j = 0; j < cnt; j += 8) {
        int i0 = start + j;
        int i1 = min(i0 + 1, last);
        int i2 = min(i0 + 2, last);
        int i3 = min(i0 + 3, last);
        int i4 = min(i0 + 4, last);
        int i5 = min(i0 + 5, last);
        int i6 = min(i0 + 6, last);
        int i7 = min(i0 + 7, last);
        int s0 = srcs[i0], s1 = srcs[i1], s2 = srcs[i2], s3 = srcs[i3];
        int s4 = srcs[i4], s5 = srcs[i5], s6 = srcs[i6], s7 = srcs[i7];
        uint32 v0 = hb[s0 * 64 + lane];
        uint32 v1 = hb[s1 * 64 + lane];
        uint32 v2 = hb[s2 * 64 + lane];
        uint32 v3 = hb[s3 * 64 + lane];
        uint32 v4 = hb[s4 * 64 + lane];
        uint32 v5 = hb[s5 * 64 + lane];
        uint32 v6 = hb[s6 * 64 + lane];
        uint32 v7 = hb[s7 * 64 + lane];
        int rem = cnt - j;
        v1 = (rem > 1) ? v1 : 0u;
        v2 = (rem > 2) ? v2 : 0u;
        v3 = (rem > 3) ? v3 : 0u;
        v4 = (rem > 4) ? v4 : 0u;
        v5 = (rem > 5) ? v5 : 0u;
        v6 = (rem > 6) ? v6 : 0u;
        v7 = (rem > 7) ? v7 : 0u;
        ax += bf_lo(v0); ay += bf_hi(v0);
        ax += bf_lo(v1); ay += bf_hi(v1);
        ax += bf_lo(v2); ay += bf_hi(v2);
        ax += bf_lo(v3); ay += bf_hi(v3);
        ax += bf_lo(v4); ay += bf_hi(v4);
        ax += bf_lo(v5); ay += bf_hi(v5);
        ax += bf_lo(v6); ay += bf_hi(v6);
        ax += bf_lo(v7); ay += bf_hi(v7);
    }
    float2 b = ((const float2*)bias)[lane];
    ax = fmaxf(ax * dn + b.x, 0.f);
    ay = fmaxf(ay * dn + b.y, 0.f);
    ((float2*)out)[node * 64 + lane] = make_float2(ax, ay);
}

// ---------------- fused mean-pool + linear (batch is sorted) ----------------
__global__ void k_pool_linear(const float* __restrict__ h, const int* __restrict__ batch,
                              const float* __restrict__ Wl, const float* __restrict__ bl,
                              float* __restrict__ out) {
    __shared__ int sb[2];
    __shared__ float xr[CH];
    int g = blockIdx.x;
    if (threadIdx.x < 2) {
        int target = g + (int)threadIdx.x;
        int lo = 0, hi = N_NODES;
        while (lo < hi) {
            int mid = (lo + hi) >> 1;
            if (batch[mid] < target) lo = mid + 1; else hi = mid;
        }
        sb[threadIdx.x] = lo;
    }
    __syncthreads();
    int lo = sb[0], hi = sb[1];
    int c = threadIdx.x;  // 128 threads
    float acc = 0.f;
    for (int i = lo; i < hi; ++i) acc += h[i * CH + c];
    float cnt = (float)((hi - lo) > 0 ? (hi - lo) : 1);
    xr[c] = acc / cnt;
    __syncthreads();
    if (c < OUT_CH) {
        float o = bl[c];
        #pragma unroll 8
        for (int k = 0; k < CH; ++k) o += xr[k] * Wl[k * OUT_CH + c];
        out[g * OUT_CH + c] = o;
    }
}

extern "C" void kernel_launch(void* const* d_in, const int* in_sizes, int n_in,
                              void* d_out, int out_size, void* d_ws, size_t ws_size,
                              hipStream_t stream) {
    const float* x    = (const float*)d_in[0];
    const float* W1   = (const float*)d_in[1];
    const float* b1   = (const float*)d_in[2];
    const float* W2   = (const float*)d_in[3];
    const float* b2   = (const float*)d_in[4];
    const float* Wlin = (const float*)d_in[5];
    const float* blin = (const float*)d_in[6];
    const int* ei     = (const int*)d_in[7];
    const int* batch  = (const int*)d_in[8];
    const int* esrc = ei;
    const int* edst = ei + N_EDGES;
    float* out = (float*)d_out;

    char* w = (char*)d_ws;
    size_t o = 0;
    float* hA     = (float*)(w + o);  o += (size_t)N_NODES * CH * 4;        // 25.6 MB fp32 (agg out)
    uint32* hb    = (uint32*)(w + o); o += (size_t)N_NODES * 64 * 4;        // 12.8 MB bf16 pre-scaled
    int* srcs     = (int*)(w + o);    o += (size_t)N_NODES * DSTRIDE * 4;   // 12.8 MB padded buckets
    float* dinv   = (float*)(w + o);  o += 200704;
    int* cur      = (int*)(w + o);    o += 200704;
    (void)ws_size; (void)in_sizes; (void)n_in; (void)out_size;

    hipMemsetAsync(cur, 0, N_NODES * sizeof(int), stream);

    dim3 b256(256);
    k_fill_pad<<<dim3((N_EDGES + 255) / 256), b256, 0, stream>>>(esrc, edst, cur, srcs);
    k_dinv<<<dim3((N_NODES + 255) / 256), b256, 0, stream>>>(cur, dinv);

    dim3 gG((N_NODES + 127) / 128);   // 391 blocks, 256 threads
    dim3 gA(N_NODES / 4);             // 12500 blocks, one wave64 per node
    k_gemm<<<gG, b256, 0, stream>>>(x, W1, dinv, hb);
    k_agg<<<gA, b256, 0, stream>>>(hb, dinv, cur, srcs, b1, hA);
    k_gemm<<<gG, b256, 0, stream>>>(hA, W2, dinv, hb);
    k_agg<<<gA, b256, 0, stream>>>(hb, dinv, cur, srcs, b2, hA);
    k_pool_linear<<<dim3(NUM_GRAPHS), dim3(128), 0, stream>>>(hA, batch, Wlin, blin, out);
}

// Round 6
// 238.362 us; speedup vs baseline: 1.9200x; 1.1461x over previous
//
#include <hip/hip_runtime.h>

#define N_NODES 50000
#define N_EDGES 600000
#define CH 128
#define NUM_GRAPHS 512
#define OUT_CH 64
// padded bucket stride (max degree safety: Poisson(12), P(>=64) ~ 0)
#define DSH 6
#define DSTRIDE 64

typedef unsigned int uint32;

// pack two fp32 -> bf16x2 (RNE), lo = first channel
__device__ __forceinline__ uint32 bfpack(float a, float b) {
    uint32 ua = __builtin_bit_cast(uint32, a);
    uint32 ub = __builtin_bit_cast(uint32, b);
    ua = (ua + 0x7fffu + ((ua >> 16) & 1u)) >> 16;
    ub = (ub + 0x7fffu + ((ub >> 16) & 1u)) >> 16;
    return (ub << 16) | ua;
}
__device__ __forceinline__ float bf_lo(uint32 v) {
    return __builtin_bit_cast(float, v << 16);
}
__device__ __forceinline__ float bf_hi(uint32 v) {
    return __builtin_bit_cast(float, v & 0xffff0000u);
}

// ---------------- padded-CSR build: one pass, no scan ----------------
__global__ void k_fill_pad(const int* __restrict__ src, const int* __restrict__ dst,
                           int* __restrict__ cur, int* __restrict__ srcs) {
    int e = blockIdx.x * 256 + threadIdx.x;
    if (e < N_EDGES) {
        int s = src[e];
        int d = dst[e];
        int p = atomicAdd(&cur[d], 1);
        srcs[(d << DSH) + p] = s;
    }
}

__global__ void k_dinv(const int* __restrict__ cur, float* __restrict__ dinv) {
    int i = blockIdx.x * 256 + threadIdx.x;
    if (i < N_NODES) dinv[i] = rsqrtf((float)(cur[i] + 1));  // +1 self-loop
}

// ---------------- dense GEMM v5: outb[N,128](bf16) = bf16(dinv*(A @ W)) ----------------
// 256 threads, block tile 128 rows x 128 cols, thread tile 4r x 16c (acc=64 regs).
// W resides fully in LDS (64 KB, staged once, one barrier). A read directly from
// global: each row belongs to exactly one wave -> 512B contiguous per row, L1/L2-hot.
__global__ __launch_bounds__(256, 2) void k_gemm(const float* __restrict__ A,
                                                 const float* __restrict__ W,
                                                 const float* __restrict__ dinv,
                                                 uint32* __restrict__ outb) {
    __shared__ float ws[CH][CH];   // 64 KB, [k][col]
    int tid = threadIdx.x;
    int cg = tid & 7;    // cols cg*4 + q*32
    int rg = tid >> 3;   // rows rg*4 + rr
    int row0 = blockIdx.x * 128;

    #pragma unroll
    for (int it = 0; it < 16; ++it) {          // 4096 float4 total
        int idx = it * 256 + tid;
        int k = idx >> 5;
        int c4 = (idx & 31) << 2;
        *(float4*)&ws[k][c4] = *(const float4*)&W[k * CH + c4];
    }
    __syncthreads();

    // clamped row pointers (duplicate compute for tail rows; stores guarded)
    const float* ap[4];
    #pragma unroll
    for (int rr = 0; rr < 4; ++rr) {
        int gr = row0 + rg * 4 + rr;
        ap[rr] = &A[(size_t)min(gr, N_NODES - 1) * CH];
    }

    float acc[4][16];
    #pragma unroll
    for (int i = 0; i < 4; ++i)
        #pragma unroll
        for (int j = 0; j < 16; ++j) acc[i][j] = 0.f;

    for (int kt = 0; kt < CH; kt += 4) {
        float4 a0 = *(const float4*)(ap[0] + kt);
        float4 a1 = *(const float4*)(ap[1] + kt);
        float4 a2 = *(const float4*)(ap[2] + kt);
        float4 a3 = *(const float4*)(ap[3] + kt);
        #pragma unroll
        for (int dk = 0; dk < 4; ++dk) {
            float4 w0 = *(float4*)&ws[kt + dk][cg * 4 + 0];
            float4 w1 = *(float4*)&ws[kt + dk][cg * 4 + 32];
            float4 w2 = *(float4*)&ws[kt + dk][cg * 4 + 64];
            float4 w3 = *(float4*)&ws[kt + dk][cg * 4 + 96];
            float v0 = (dk == 0) ? a0.x : (dk == 1) ? a0.y : (dk == 2) ? a0.z : a0.w;
            float v1 = (dk == 0) ? a1.x : (dk == 1) ? a1.y : (dk == 2) ? a1.z : a1.w;
            float v2 = (dk == 0) ? a2.x : (dk == 1) ? a2.y : (dk == 2) ? a2.z : a2.w;
            float v3 = (dk == 0) ? a3.x : (dk == 1) ? a3.y : (dk == 2) ? a3.z : a3.w;
            acc[0][0]  += v0 * w0.x; acc[0][1]  += v0 * w0.y;
            acc[0][2]  += v0 * w0.z; acc[0][3]  += v0 * w0.w;
            acc[0][4]  += v0 * w1.x; acc[0][5]  += v0 * w1.y;
            acc[0][6]  += v0 * w1.z; acc[0][7]  += v0 * w1.w;
            acc[0][8]  += v0 * w2.x; acc[0][9]  += v0 * w2.y;
            acc[0][10] += v0 * w2.z; acc[0][11] += v0 * w2.w;
            acc[0][12] += v0 * w3.x; acc[0][13] += v0 * w3.y;
            acc[0][14] += v0 * w3.z; acc[0][15] += v0 * w3.w;
            acc[1][0]  += v1 * w0.x; acc[1][1]  += v1 * w0.y;
            acc[1][2]  += v1 * w0.z; acc[1][3]  += v1 * w0.w;
            acc[1][4]  += v1 * w1.x; acc[1][5]  += v1 * w1.y;
            acc[1][6]  += v1 * w1.z; acc[1][7]  += v1 * w1.w;
            acc[1][8]  += v1 * w2.x; acc[1][9]  += v1 * w2.y;
            acc[1][10] += v1 * w2.z; acc[1][11] += v1 * w2.w;
            acc[1][12] += v1 * w3.x; acc[1][13] += v1 * w3.y;
            acc[1][14] += v1 * w3.z; acc[1][15] += v1 * w3.w;
            acc[2][0]  += v2 * w0.x; acc[2][1]  += v2 * w0.y;
            acc[2][2]  += v2 * w0.z; acc[2][3]  += v2 * w0.w;
            acc[2][4]  += v2 * w1.x; acc[2][5]  += v2 * w1.y;
            acc[2][6]  += v2 * w1.z; acc[2][7]  += v2 * w1.w;
            acc[2][8]  += v2 * w2.x; acc[2][9]  += v2 * w2.y;
            acc[2][10] += v2 * w2.z; acc[2][11] += v2 * w2.w;
            acc[2][12] += v2 * w3.x; acc[2][13] += v2 * w3.y;
            acc[2][14] += v2 * w3.z; acc[2][15] += v2 * w3.w;
            acc[3][0]  += v3 * w0.x; acc[3][1]  += v3 * w0.y;
            acc[3][2]  += v3 * w0.z; acc[3][3]  += v3 * w0.w;
            acc[3][4]  += v3 * w1.x; acc[3][5]  += v3 * w1.y;
            acc[3][6]  += v3 * w1.z; acc[3][7]  += v3 * w1.w;
            acc[3][8]  += v3 * w2.x; acc[3][9]  += v3 * w2.y;
            acc[3][10] += v3 * w2.z; acc[3][11] += v3 * w2.w;
            acc[3][12] += v3 * w3.x; acc[3][13] += v3 * w3.y;
            acc[3][14] += v3 * w3.z; acc[3][15] += v3 * w3.w;
        }
    }

    #pragma unroll
    for (int rr = 0; rr < 4; ++rr) {
        int gr = row0 + rg * 4 + rr;
        if (gr < N_NODES) {
            float sc = dinv[gr];
            #pragma unroll
            for (int q = 0; q < 4; ++q) {
                uint32 p0 = bfpack(acc[rr][q * 4 + 0] * sc, acc[rr][q * 4 + 1] * sc);
                uint32 p1 = bfpack(acc[rr][q * 4 + 2] * sc, acc[rr][q * 4 + 3] * sc);
                *(uint2*)&outb[gr * 64 + cg * 2 + q * 16] = make_uint2(p0, p1);
            }
        }
    }
}

// ---------------- aggregation v5: padded buckets, pure bf16 gathers ----------------
__global__ __launch_bounds__(256) void k_agg(const uint32* __restrict__ hb,
                                             const float* __restrict__ dinv,
                                             const int* __restrict__ cnt_arr,
                                             const int* __restrict__ srcs,
                                             const float* __restrict__ bias,
                                             float* __restrict__ out) {
    int node = __builtin_amdgcn_readfirstlane(blockIdx.x * 4 + (threadIdx.x >> 6));
    int lane = threadIdx.x & 63;

    float dn = dinv[node];
    uint32 vs = hb[node * 64 + lane];       // self-loop: bf16(dinv[n]*h[n])
    float ax = bf_lo(vs), ay = bf_hi(vs);

    int start = node << DSH;
    int cnt = cnt_arr[node];
    int last = start + cnt - 1;
    for (int j = 0; j < cnt; j += 8) {
        int i0 = start + j;
        int i1 = min(i0 + 1, last);
        int i2 = min(i0 + 2, last);
        int i3 = min(i0 + 3, last);
        int i4 = min(i0 + 4, last);
        int i5 = min(i0 + 5, last);
        int i6 = min(i0 + 6, last);
        int i7 = min(i0 + 7, last);
        int s0 = srcs[i0], s1 = srcs[i1], s2 = srcs[i2], s3 = srcs[i3];
        int s4 = srcs[i4], s5 = srcs[i5], s6 = srcs[i6], s7 = srcs[i7];
        uint32 v0 = hb[s0 * 64 + lane];
        uint32 v1 = hb[s1 * 64 + lane];
        uint32 v2 = hb[s2 * 64 + lane];
        uint32 v3 = hb[s3 * 64 + lane];
        uint32 v4 = hb[s4 * 64 + lane];
        uint32 v5 = hb[s5 * 64 + lane];
        uint32 v6 = hb[s6 * 64 + lane];
        uint32 v7 = hb[s7 * 64 + lane];
        int rem = cnt - j;
        v1 = (rem > 1) ? v1 : 0u;
        v2 = (rem > 2) ? v2 : 0u;
        v3 = (rem > 3) ? v3 : 0u;
        v4 = (rem > 4) ? v4 : 0u;
        v5 = (rem > 5) ? v5 : 0u;
        v6 = (rem > 6) ? v6 : 0u;
        v7 = (rem > 7) ? v7 : 0u;
        ax += bf_lo(v0); ay += bf_hi(v0);
        ax += bf_lo(v1); ay += bf_hi(v1);
        ax += bf_lo(v2); ay += bf_hi(v2);
        ax += bf_lo(v3); ay += bf_hi(v3);
        ax += bf_lo(v4); ay += bf_hi(v4);
        ax += bf_lo(v5); ay += bf_hi(v5);
        ax += bf_lo(v6); ay += bf_hi(v6);
        ax += bf_lo(v7); ay += bf_hi(v7);
    }
    float2 b = ((const float2*)bias)[lane];
    ax = fmaxf(ax * dn + b.x, 0.f);
    ay = fmaxf(ay * dn + b.y, 0.f);
    ((float2*)out)[node * 64 + lane] = make_float2(ax, ay);
}

// ---------------- fused mean-pool + linear v2 (batch is sorted) ----------------
// 256 threads: thread (q = tid&31, r = tid>>5) accumulates float4 channel-quad q
// over rows lo+r, lo+r+8, ... -> 8 rows x 32 lanes in flight, coalesced.
// LDS-reduce 8 row-partials, then 64-col linear with k split 4 ways.
__global__ __launch_bounds__(256) void k_pool_linear(const float* __restrict__ h,
                                                     const int* __restrict__ batch,
                                                     const float* __restrict__ Wl,
                                                     const float* __restrict__ bl,
                                                     float* __restrict__ out) {
    __shared__ int sb[2];
    __shared__ float4 sacc[256];
    __shared__ float xr[CH];
    __shared__ float po[4][OUT_CH];
    int g = blockIdx.x;
    int tid = threadIdx.x;
    if (tid < 2) {
        int target = g + tid;
        int lo = 0, hi = N_NODES;
        while (lo < hi) {
            int mid = (lo + hi) >> 1;
            if (batch[mid] < target) lo = mid + 1; else hi = mid;
        }
        sb[tid] = lo;
    }
    __syncthreads();
    int lo = sb[0], hi = sb[1];
    int q = tid & 31;   // channel quad
    int r = tid >> 5;   // row phase 0..7
    const float4* h4 = (const float4*)h;
    float4 acc = make_float4(0.f, 0.f, 0.f, 0.f);
    for (int i = lo + r; i < hi; i += 8) {
        float4 v = h4[(size_t)i * 32 + q];
        acc.x += v.x; acc.y += v.y; acc.z += v.z; acc.w += v.w;
    }
    sacc[tid] = acc;
    __syncthreads();
    if (r == 0) {
        #pragma unroll
        for (int p = 1; p < 8; ++p) {
            float4 t = sacc[q + p * 32];
            acc.x += t.x; acc.y += t.y; acc.z += t.z; acc.w += t.w;
        }
        float inv = 1.f / (float)((hi - lo) > 0 ? (hi - lo) : 1);
        xr[q * 4 + 0] = acc.x * inv;
        xr[q * 4 + 1] = acc.y * inv;
        xr[q * 4 + 2] = acc.z * inv;
        xr[q * 4 + 3] = acc.w * inv;
    }
    __syncthreads();
    // linear: 256 threads = (c = tid&63, kh = tid>>6), each does 32 k-terms
    int c = tid & 63;
    int kh = tid >> 6;
    float o = 0.f;
    #pragma unroll 8
    for (int k = kh * 32; k < kh * 32 + 32; ++k) o += xr[k] * Wl[k * OUT_CH + c];
    po[kh][c] = o;
    __syncthreads();
    if (tid < OUT_CH) {
        float v = bl[tid] + po[0][tid] + po[1][tid] + po[2][tid] + po[3][tid];
        out[g * OUT_CH + tid] = v;
    }
}

extern "C" void kernel_launch(void* const* d_in, const int* in_sizes, int n_in,
                              void* d_out, int out_size, void* d_ws, size_t ws_size,
                              hipStream_t stream) {
    const float* x    = (const float*)d_in[0];
    const float* W1   = (const float*)d_in[1];
    const float* b1   = (const float*)d_in[2];
    const float* W2   = (const float*)d_in[3];
    const float* b2   = (const float*)d_in[4];
    const float* Wlin = (const float*)d_in[5];
    const float* blin = (const float*)d_in[6];
    const int* ei     = (const int*)d_in[7];
    const int* batch  = (const int*)d_in[8];
    const int* esrc = ei;
    const int* edst = ei + N_EDGES;
    float* out = (float*)d_out;

    char* w = (char*)d_ws;
    size_t o = 0;
    float* hA     = (float*)(w + o);  o += (size_t)N_NODES * CH * 4;        // 25.6 MB fp32 (agg out)
    uint32* hb    = (uint32*)(w + o); o += (size_t)N_NODES * 64 * 4;        // 12.8 MB bf16 pre-scaled
    int* srcs     = (int*)(w + o);    o += (size_t)N_NODES * DSTRIDE * 4;   // 12.8 MB padded buckets
    float* dinv   = (float*)(w + o);  o += 200704;
    int* cur      = (int*)(w + o);    o += 200704;
    (void)ws_size; (void)in_sizes; (void)n_in; (void)out_size;

    hipMemsetAsync(cur, 0, N_NODES * sizeof(int), stream);

    dim3 b256(256);
    k_fill_pad<<<dim3((N_EDGES + 255) / 256), b256, 0, stream>>>(esrc, edst, cur, srcs);
    k_dinv<<<dim3((N_NODES + 255) / 256), b256, 0, stream>>>(cur, dinv);

    dim3 gG((N_NODES + 127) / 128);   // 391 blocks, 256 threads
    dim3 gA(N_NODES / 4);             // 12500 blocks, one wave64 per node
    k_gemm<<<gG, b256, 0, stream>>>(x, W1, dinv, hb);
    k_agg<<<gA, b256, 0, stream>>>(hb, dinv, cur, srcs, b1, hA);
    k_gemm<<<gG, b256, 0, stream>>>(hA, W2, dinv, hb);
    k_agg<<<gA, b256, 0, stream>>>(hb, dinv, cur, srcs, b2, hA);
    k_pool_linear<<<dim3(NUM_GRAPHS), b256, 0, stream>>>(hA, batch, Wlin, blin, out);
}

// Round 7
// 204.965 us; speedup vs baseline: 2.2329x; 1.1629x over previous
//
#include <hip/hip_runtime.h>

#define N_NODES 50000
#define N_EDGES 600000
#define CH 128
#define NUM_GRAPHS 512
#define OUT_CH 64
// padded bucket stride (max degree safety: Poisson(12), P(>=64) ~ 0)
#define DSH 6
#define DSTRIDE 64

typedef unsigned int uint32;
typedef unsigned short ushort16_t;
typedef __attribute__((ext_vector_type(8))) short short8;
typedef __attribute__((ext_vector_type(4))) float floatx4;

// pack two fp32 -> bf16x2 (RNE), lo = first channel
__device__ __forceinline__ uint32 bfpack(float a, float b) {
    uint32 ua = __builtin_bit_cast(uint32, a);
    uint32 ub = __builtin_bit_cast(uint32, b);
    ua = (ua + 0x7fffu + ((ua >> 16) & 1u)) >> 16;
    ub = (ub + 0x7fffu + ((ub >> 16) & 1u)) >> 16;
    return (ub << 16) | ua;
}
__device__ __forceinline__ unsigned short bfr(float f) {
    uint32 u = __builtin_bit_cast(uint32, f);
    u = (u + 0x7fffu + ((u >> 16) & 1u)) >> 16;
    return (unsigned short)u;
}
__device__ __forceinline__ float bf_lo(uint32 v) {
    return __builtin_bit_cast(float, v << 16);
}
__device__ __forceinline__ float bf_hi(uint32 v) {
    return __builtin_bit_cast(float, v & 0xffff0000u);
}

// ---------------- padded-CSR build: one pass, no scan ----------------
__global__ void k_fill_pad(const int* __restrict__ src, const int* __restrict__ dst,
                           int* __restrict__ cur, int* __restrict__ srcs) {
    int e = blockIdx.x * 256 + threadIdx.x;
    if (e < N_EDGES) {
        int s = src[e];
        int d = dst[e];
        int p = atomicAdd(&cur[d], 1);
        srcs[(d << DSH) + p] = s;
    }
}

// ---------------- x -> bf16 cast ----------------
__global__ void k_cast(const float4* __restrict__ x, uint2* __restrict__ xb, int n4) {
    int i = blockIdx.x * 256 + threadIdx.x;
    if (i < n4) {
        float4 v = x[i];
        xb[i] = make_uint2(bfpack(v.x, v.y), bfpack(v.z, v.w));
    }
}

// ---------------- W1,W2 -> bf16 transposed (Wt[c][k]) ----------------
__global__ void k_prep(const float* __restrict__ W1, const float* __restrict__ W2,
                       unsigned short* __restrict__ W1t, unsigned short* __restrict__ W2t) {
    int idx = blockIdx.x * 256 + threadIdx.x;   // 32768 total
    int mat = idx >> 14;
    int rem = idx & 16383;
    int k = rem >> 7, c = rem & 127;
    const float* W = mat ? W2 : W1;
    unsigned short* Wt = mat ? W2t : W1t;
    Wt[c * 128 + k] = bfr(W[k * 128 + c]);
}

// ---------------- MFMA GEMM: outb[N,128](bf16) = bf16(dinv * (A @ W)) ----------------
// A: bf16 rows [N][128]. Wt: bf16 transposed [col][k]. 256 thr = 4 waves,
// block tile 128x128; wave = 2 row-tiles x 8 col-tiles of 16x16x32 MFMA.
// Layouts (verified, learn_hip m89/m91/m120): A-frag [m=lane&15][k=quad*8+j],
// B-frag [n=lane&15][k=quad*8+j] (from Wt), C/D row=quad*4+reg, col=lane&15.
__global__ __launch_bounds__(256, 2) void k_gemm(const unsigned short* __restrict__ Ab,
                                                 const unsigned short* __restrict__ Wt,
                                                 const int* __restrict__ cur,
                                                 unsigned short* __restrict__ outb) {
    __shared__ __align__(16) unsigned short as_[128][136];  // +8 pad: stride 272B
    __shared__ __align__(16) unsigned short bs[128][136];
    int tid = threadIdx.x;
    int row0 = blockIdx.x * 128;

    #pragma unroll
    for (int it = 0; it < 8; ++it) {            // A tile: 128 rows x 256B
        int idx = it * 256 + tid;
        int r = idx >> 4, seg = idx & 15;
        int gr = min(row0 + r, N_NODES - 1);
        *(uint4*)&as_[r][seg * 8] = *(const uint4*)&Ab[(size_t)gr * 128 + seg * 8];
    }
    #pragma unroll
    for (int it = 0; it < 8; ++it) {            // Wt tile: 128 cols x 256B
        int idx = it * 256 + tid;
        int c = idx >> 4, seg = idx & 15;
        *(uint4*)&bs[c][seg * 8] = *(const uint4*)&Wt[c * 128 + seg * 8];
    }
    __syncthreads();

    int w = tid >> 6, lane = tid & 63, q = lane >> 4, m = lane & 15;
    int q8 = q * 8;
    floatx4 acc[2][8];
    #pragma unroll
    for (int rt = 0; rt < 2; ++rt)
        #pragma unroll
        for (int ct = 0; ct < 8; ++ct) {
            floatx4 z = {0.f, 0.f, 0.f, 0.f};
            acc[rt][ct] = z;
        }

    #pragma unroll
    for (int kc = 0; kc < 128; kc += 32) {
        short8 a0 = *(const short8*)&as_[w * 32 + m][kc + q8];
        short8 a1 = *(const short8*)&as_[w * 32 + 16 + m][kc + q8];
        #pragma unroll
        for (int ct = 0; ct < 8; ++ct) {
            short8 b = *(const short8*)&bs[ct * 16 + m][kc + q8];
            acc[0][ct] = __builtin_amdgcn_mfma_f32_16x16x32_bf16(a0, b, acc[0][ct], 0, 0, 0);
            acc[1][ct] = __builtin_amdgcn_mfma_f32_16x16x32_bf16(a1, b, acc[1][ct], 0, 0, 0);
        }
    }

    #pragma unroll
    for (int rt = 0; rt < 2; ++rt) {
        #pragma unroll
        for (int i = 0; i < 4; ++i) {
            int gr = row0 + w * 32 + rt * 16 + q * 4 + i;
            if (gr < N_NODES) {
                float sc = rsqrtf((float)(cur[gr] + 1));
                #pragma unroll
                for (int ct = 0; ct < 8; ++ct) {
                    outb[(size_t)gr * 128 + ct * 16 + m] = bfr(acc[rt][ct][i] * sc);
                }
            }
        }
    }
}

// ---------------- aggregation: padded buckets, pure bf16 gathers ----------------
// a[d] = sum_{s in bucket} hb[s] + hb[d];  act = relu(dn*a + b)
// outB (bf16, layer1 -> gemm2 input) / outF (fp32, layer2 -> pool) selectable.
__global__ __launch_bounds__(256) void k_agg(const uint32* __restrict__ hb,
                                             const int* __restrict__ cnt_arr,
                                             const int* __restrict__ srcs,
                                             const float* __restrict__ bias,
                                             uint32* __restrict__ outB,
                                             float2* __restrict__ outF) {
    int node = __builtin_amdgcn_readfirstlane(blockIdx.x * 4 + (threadIdx.x >> 6));
    int lane = threadIdx.x & 63;

    int cnt = cnt_arr[node];
    float dn = rsqrtf((float)(cnt + 1));
    uint32 vs = hb[node * 64 + lane];       // self-loop: bf16(dinv[n]*h[n])
    float ax = bf_lo(vs), ay = bf_hi(vs);

    int start = node << DSH;
    int last = start + cnt - 1;
    for (int j = 0; j < cnt; j += 8) {
        int i0 = start + j;
        int i1 = min(i0 + 1, last);
        int i2 = min(i0 + 2, last);
        int i3 = min(i0 + 3, last);
        int i4 = min(i0 + 4, last);
        int i5 = min(i0 + 5, last);
        int i6 = min(i0 + 6, last);
        int i7 = min(i0 + 7, last);
        int s0 = srcs[i0], s1 = srcs[i1], s2 = srcs[i2], s3 = srcs[i3];
        int s4 = srcs[i4], s5 = srcs[i5], s6 = srcs[i6], s7 = srcs[i7];
        uint32 v0 = hb[s0 * 64 + lane];
        uint32 v1 = hb[s1 * 64 + lane];
        uint32 v2 = hb[s2 * 64 + lane];
        uint32 v3 = hb[s3 * 64 + lane];
        uint32 v4 = hb[s4 * 64 + lane];
        uint32 v5 = hb[s5 * 64 + lane];
        uint32 v6 = hb[s6 * 64 + lane];
        uint32 v7 = hb[s7 * 64 + lane];
        int rem = cnt - j;
        v1 = (rem > 1) ? v1 : 0u;
        v2 = (rem > 2) ? v2 : 0u;
        v3 = (rem > 3) ? v3 : 0u;
        v4 = (rem > 4) ? v4 : 0u;
        v5 = (rem > 5) ? v5 : 0u;
        v6 = (rem > 6) ? v6 : 0u;
        v7 = (rem > 7) ? v7 : 0u;
        ax += bf_lo(v0); ay += bf_hi(v0);
        ax += bf_lo(v1); ay += bf_hi(v1);
        ax += bf_lo(v2); ay += bf_hi(v2);
        ax += bf_lo(v3); ay += bf_hi(v3);
        ax += bf_lo(v4); ay += bf_hi(v4);
        ax += bf_lo(v5); ay += bf_hi(v5);
        ax += bf_lo(v6); ay += bf_hi(v6);
        ax += bf_lo(v7); ay += bf_hi(v7);
    }
    float2 b = ((const float2*)bias)[lane];
    ax = fmaxf(ax * dn + b.x, 0.f);
    ay = fmaxf(ay * dn + b.y, 0.f);
    if (outB) outB[node * 64 + lane] = bfpack(ax, ay);
    if (outF) outF[node * 64 + lane] = make_float2(ax, ay);
}

// ---------------- fused mean-pool + linear (batch is sorted) ----------------
__global__ __launch_bounds__(256) void k_pool_linear(const float* __restrict__ h,
                                                     const int* __restrict__ batch,
                                                     const float* __restrict__ Wl,
                                                     const float* __restrict__ bl,
                                                     float* __restrict__ out) {
    __shared__ int sb[2];
    __shared__ float4 sacc[256];
    __shared__ float xr[CH];
    __shared__ float po[4][OUT_CH];
    int g = blockIdx.x;
    int tid = threadIdx.x;
    if (tid < 2) {
        int target = g + tid;
        int lo = 0, hi = N_NODES;
        while (lo < hi) {
            int mid = (lo + hi) >> 1;
            if (batch[mid] < target) lo = mid + 1; else hi = mid;
        }
        sb[tid] = lo;
    }
    __syncthreads();
    int lo = sb[0], hi = sb[1];
    int q = tid & 31;   // channel quad
    int r = tid >> 5;   // row phase 0..7
    const float4* h4 = (const float4*)h;
    float4 acc = make_float4(0.f, 0.f, 0.f, 0.f);
    for (int i = lo + r; i < hi; i += 8) {
        float4 v = h4[(size_t)i * 32 + q];
        acc.x += v.x; acc.y += v.y; acc.z += v.z; acc.w += v.w;
    }
    sacc[tid] = acc;
    __syncthreads();
    if (r == 0) {
        #pragma unroll
        for (int p = 1; p < 8; ++p) {
            float4 t = sacc[q + p * 32];
            acc.x += t.x; acc.y += t.y; acc.z += t.z; acc.w += t.w;
        }
        float inv = 1.f / (float)((hi - lo) > 0 ? (hi - lo) : 1);
        xr[q * 4 + 0] = acc.x * inv;
        xr[q * 4 + 1] = acc.y * inv;
        xr[q * 4 + 2] = acc.z * inv;
        xr[q * 4 + 3] = acc.w * inv;
    }
    __syncthreads();
    int c = tid & 63;
    int kh = tid >> 6;
    float o = 0.f;
    #pragma unroll 8
    for (int k = kh * 32; k < kh * 32 + 32; ++k) o += xr[k] * Wl[k * OUT_CH + c];
    po[kh][c] = o;
    __syncthreads();
    if (tid < OUT_CH) {
        float v = bl[tid] + po[0][tid] + po[1][tid] + po[2][tid] + po[3][tid];
        out[g * OUT_CH + tid] = v;
    }
}

extern "C" void kernel_launch(void* const* d_in, const int* in_sizes, int n_in,
                              void* d_out, int out_size, void* d_ws, size_t ws_size,
                              hipStream_t stream) {
    const float* x    = (const float*)d_in[0];
    const float* W1   = (const float*)d_in[1];
    const float* b1   = (const float*)d_in[2];
    const float* W2   = (const float*)d_in[3];
    const float* b2   = (const float*)d_in[4];
    const float* Wlin = (const float*)d_in[5];
    const float* blin = (const float*)d_in[6];
    const int* ei     = (const int*)d_in[7];
    const int* batch  = (const int*)d_in[8];
    const int* esrc = ei;
    const int* edst = ei + N_EDGES;
    float* out = (float*)d_out;

    char* w = (char*)d_ws;
    size_t o = 0;
    float* hA            = (float*)(w + o);          o += (size_t)N_NODES * CH * 4;      // fp32 agg2 out
    unsigned short* hb   = (unsigned short*)(w + o); o += (size_t)N_NODES * CH * 2;      // bf16 prescaled gemm out
    uint32* habf         = (uint32*)(w + o);         o += (size_t)N_NODES * 64 * 4;      // bf16 agg1 out
    unsigned short* xb   = (unsigned short*)(w + o); o += (size_t)N_NODES * CH * 2;      // bf16 x
    unsigned short* W1t  = (unsigned short*)(w + o); o += 16384 * 2;
    unsigned short* W2t  = (unsigned short*)(w + o); o += 16384 * 2;
    int* srcs            = (int*)(w + o);            o += (size_t)N_NODES * DSTRIDE * 4; // padded buckets
    int* cur             = (int*)(w + o);            o += 200704;
    (void)ws_size; (void)in_sizes; (void)n_in; (void)out_size;

    hipMemsetAsync(cur, 0, N_NODES * sizeof(int), stream);

    dim3 b256(256);
    k_fill_pad<<<dim3((N_EDGES + 255) / 256), b256, 0, stream>>>(esrc, edst, cur, srcs);
    k_cast<<<dim3(N_NODES * CH / 4 / 256), b256, 0, stream>>>((const float4*)x, (uint2*)xb,
                                                              N_NODES * CH / 4);
    k_prep<<<dim3(128), b256, 0, stream>>>(W1, W2, W1t, W2t);

    dim3 gG((N_NODES + 127) / 128);   // 391 blocks
    dim3 gA(N_NODES / 4);             // 12500 blocks, one wave64 per node
    k_gemm<<<gG, b256, 0, stream>>>(xb, W1t, cur, hb);
    k_agg<<<gA, b256, 0, stream>>>((const uint32*)hb, cur, srcs, b1, habf, nullptr);
    k_gemm<<<gG, b256, 0, stream>>>((const unsigned short*)habf, W2t, cur, hb);
    k_agg<<<gA, b256, 0, stream>>>((const uint32*)hb, cur, srcs, b2, nullptr, (float2*)hA);
    k_pool_linear<<<dim3(NUM_GRAPHS), b256, 0, stream>>>(hA, batch, Wlin, blin, out);
}

// Round 8
// 198.419 us; speedup vs baseline: 2.3065x; 1.0330x over previous
//
#include <hip/hip_runtime.h>

#define N_NODES 50000
#define N_EDGES 600000
#define CH 128
#define NUM_GRAPHS 512
#define OUT_CH 64
// padded bucket stride (max degree safety: Poisson(12), P(>=64) ~ 0)
#define DSH 6
#define DSTRIDE 64

typedef unsigned int uint32;
typedef __attribute__((ext_vector_type(8))) short short8;
typedef __attribute__((ext_vector_type(4))) float floatx4;

// pack two fp32 -> bf16x2 (RNE), lo = first channel
__device__ __forceinline__ uint32 bfpack(float a, float b) {
    uint32 ua = __builtin_bit_cast(uint32, a);
    uint32 ub = __builtin_bit_cast(uint32, b);
    ua = (ua + 0x7fffu + ((ua >> 16) & 1u)) >> 16;
    ub = (ub + 0x7fffu + ((ub >> 16) & 1u)) >> 16;
    return (ub << 16) | ua;
}
__device__ __forceinline__ unsigned short bfr(float f) {
    uint32 u = __builtin_bit_cast(uint32, f);
    u = (u + 0x7fffu + ((u >> 16) & 1u)) >> 16;
    return (unsigned short)u;
}
__device__ __forceinline__ float bf_lo(uint32 v) {
    return __builtin_bit_cast(float, v << 16);
}
__device__ __forceinline__ float bf_hi(uint32 v) {
    return __builtin_bit_cast(float, v & 0xffff0000u);
}

// ---------------- prep: zero cur + W1,W2 -> bf16 transposed (Wt[c][k]) ----------------
// grid 196 x 256 = 50176 threads
__global__ void k_prep(const float* __restrict__ W1, const float* __restrict__ W2,
                       unsigned short* __restrict__ W1t, unsigned short* __restrict__ W2t,
                       int* __restrict__ cur) {
    int idx = blockIdx.x * 256 + threadIdx.x;
    if (idx < N_NODES) cur[idx] = 0;
    if (idx < 32768) {
        int mat = idx >> 14;
        int rem = idx & 16383;
        int k = rem >> 7, c = rem & 127;
        const float* W = mat ? W2 : W1;
        unsigned short* Wt = mat ? W2t : W1t;
        Wt[c * 128 + k] = bfr(W[k * 128 + c]);
    }
}

// ---------------- padded-CSR build: one pass, no scan, 4 edges/thread ----------------
__global__ void k_fill_pad(const int4* __restrict__ src4, const int4* __restrict__ dst4,
                           int* __restrict__ cur, int* __restrict__ srcs) {
    int e4 = blockIdx.x * 256 + threadIdx.x;
    if (e4 < N_EDGES / 4) {
        int4 s = src4[e4];
        int4 d = dst4[e4];
        int p;
        p = atomicAdd(&cur[d.x], 1); srcs[(d.x << DSH) + p] = s.x;
        p = atomicAdd(&cur[d.y], 1); srcs[(d.y << DSH) + p] = s.y;
        p = atomicAdd(&cur[d.z], 1); srcs[(d.z << DSH) + p] = s.z;
        p = atomicAdd(&cur[d.w], 1); srcs[(d.w << DSH) + p] = s.w;
    }
}

// ---------------- MFMA GEMM: outb[N,128](bf16) = bf16(dinv * (A @ W)) ----------------
// A: fp32 [N][128] (AF32=true, packs to bf16 during staging) or bf16 [N][128].
// Wt: bf16 transposed [col][k]. 256 thr = 4 waves, block tile 128x128;
// wave = 2 row-tiles x 8 col-tiles of 16x16x32 MFMA.
// Layouts (verified, learn_hip m89/m91/m120): A-frag [m=lane&15][k=quad*8+j],
// B-frag [n=lane&15][k=quad*8+j] (from Wt), C/D row=quad*4+reg, col=lane&15.
template <bool AF32>
__global__ __launch_bounds__(256, 2) void k_gemm(const void* __restrict__ Av,
                                                 const unsigned short* __restrict__ Wt,
                                                 const int* __restrict__ cur,
                                                 unsigned short* __restrict__ outb) {
    __shared__ __align__(16) unsigned short as_[128][136];  // +8 pad: stride 272B
    __shared__ __align__(16) unsigned short bs[128][136];
    int tid = threadIdx.x;
    int row0 = blockIdx.x * 128;

    #pragma unroll
    for (int it = 0; it < 8; ++it) {            // A tile: 128 rows x 16 segs x 8 ch
        int idx = it * 256 + tid;
        int r = idx >> 4, seg = idx & 15;
        int gr = min(row0 + r, N_NODES - 1);
        if (AF32) {
            const float4* ap = (const float4*)((const float*)Av + (size_t)gr * 128 + seg * 8);
            float4 v0 = ap[0], v1 = ap[1];
            uint4 pk;
            pk.x = bfpack(v0.x, v0.y); pk.y = bfpack(v0.z, v0.w);
            pk.z = bfpack(v1.x, v1.y); pk.w = bfpack(v1.z, v1.w);
            *(uint4*)&as_[r][seg * 8] = pk;
        } else {
            *(uint4*)&as_[r][seg * 8] =
                *(const uint4*)((const unsigned short*)Av + (size_t)gr * 128 + seg * 8);
        }
    }
    #pragma unroll
    for (int it = 0; it < 8; ++it) {            // Wt tile: 128 cols x 256B
        int idx = it * 256 + tid;
        int c = idx >> 4, seg = idx & 15;
        *(uint4*)&bs[c][seg * 8] = *(const uint4*)&Wt[c * 128 + seg * 8];
    }
    __syncthreads();

    int w = tid >> 6, lane = tid & 63, q = lane >> 4, m = lane & 15;
    int q8 = q * 8;
    floatx4 acc[2][8];
    #pragma unroll
    for (int rt = 0; rt < 2; ++rt)
        #pragma unroll
        for (int ct = 0; ct < 8; ++ct) {
            floatx4 z = {0.f, 0.f, 0.f, 0.f};
            acc[rt][ct] = z;
        }

    #pragma unroll
    for (int kc = 0; kc < 128; kc += 32) {
        short8 a0 = *(const short8*)&as_[w * 32 + m][kc + q8];
        short8 a1 = *(const short8*)&as_[w * 32 + 16 + m][kc + q8];
        #pragma unroll
        for (int ct = 0; ct < 8; ++ct) {
            short8 b = *(const short8*)&bs[ct * 16 + m][kc + q8];
            acc[0][ct] = __builtin_amdgcn_mfma_f32_16x16x32_bf16(a0, b, acc[0][ct], 0, 0, 0);
            acc[1][ct] = __builtin_amdgcn_mfma_f32_16x16x32_bf16(a1, b, acc[1][ct], 0, 0, 0);
        }
    }

    #pragma unroll
    for (int rt = 0; rt < 2; ++rt) {
        #pragma unroll
        for (int i = 0; i < 4; ++i) {
            int gr = row0 + w * 32 + rt * 16 + q * 4 + i;
            if (gr < N_NODES) {
                float sc = rsqrtf((float)(cur[gr] + 1));
                #pragma unroll
                for (int ct = 0; ct < 8; ++ct) {
                    outb[(size_t)gr * 128 + ct * 16 + m] = bfr(acc[rt][ct][i] * sc);
                }
            }
        }
    }
}

// ---------------- aggregation: padded buckets, pure bf16 gathers ----------------
// a[d] = sum_{s in bucket} hb[s] + hb[d];  act = relu(dn*a + b)
// BF16OUT: bf16 (layer1 -> gemm2 input); else fp32 (layer2 -> pool).
template <bool BF16OUT>
__global__ __launch_bounds__(256) void k_agg(const uint32* __restrict__ hb,
                                             const int* __restrict__ cnt_arr,
                                             const int* __restrict__ srcs,
                                             const float* __restrict__ bias,
                                             void* __restrict__ outv) {
    int node = __builtin_amdgcn_readfirstlane(blockIdx.x * 4 + (threadIdx.x >> 6));
    int lane = threadIdx.x & 63;

    int cnt = cnt_arr[node];
    float dn = rsqrtf((float)(cnt + 1));
    uint32 vs = hb[node * 64 + lane];       // self-loop: bf16(dinv[n]*h[n])
    float ax = bf_lo(vs), ay = bf_hi(vs);

    int start = node << DSH;
    int last = start + cnt - 1;
    for (int j = 0; j < cnt; j += 8) {
        int i0 = start + j;
        int i1 = min(i0 + 1, last);
        int i2 = min(i0 + 2, last);
        int i3 = min(i0 + 3, last);
        int i4 = min(i0 + 4, last);
        int i5 = min(i0 + 5, last);
        int i6 = min(i0 + 6, last);
        int i7 = min(i0 + 7, last);
        int s0 = srcs[i0], s1 = srcs[i1], s2 = srcs[i2], s3 = srcs[i3];
        int s4 = srcs[i4], s5 = srcs[i5], s6 = srcs[i6], s7 = srcs[i7];
        uint32 v0 = hb[s0 * 64 + lane];
        uint32 v1 = hb[s1 * 64 + lane];
        uint32 v2 = hb[s2 * 64 + lane];
        uint32 v3 = hb[s3 * 64 + lane];
        uint32 v4 = hb[s4 * 64 + lane];
        uint32 v5 = hb[s5 * 64 + lane];
        uint32 v6 = hb[s6 * 64 + lane];
        uint32 v7 = hb[s7 * 64 + lane];
        int rem = cnt - j;
        v1 = (rem > 1) ? v1 : 0u;
        v2 = (rem > 2) ? v2 : 0u;
        v3 = (rem > 3) ? v3 : 0u;
        v4 = (rem > 4) ? v4 : 0u;
        v5 = (rem > 5) ? v5 : 0u;
        v6 = (rem > 6) ? v6 : 0u;
        v7 = (rem > 7) ? v7 : 0u;
        ax += bf_lo(v0); ay += bf_hi(v0);
        ax += bf_lo(v1); ay += bf_hi(v1);
        ax += bf_lo(v2); ay += bf_hi(v2);
        ax += bf_lo(v3); ay += bf_hi(v3);
        ax += bf_lo(v4); ay += bf_hi(v4);
        ax += bf_lo(v5); ay += bf_hi(v5);
        ax += bf_lo(v6); ay += bf_hi(v6);
        ax += bf_lo(v7); ay += bf_hi(v7);
    }
    float2 b = ((const float2*)bias)[lane];
    ax = fmaxf(ax * dn + b.x, 0.f);
    ay = fmaxf(ay * dn + b.y, 0.f);
    if (BF16OUT) ((uint32*)outv)[node * 64 + lane] = bfpack(ax, ay);
    else         ((float2*)outv)[node * 64 + lane] = make_float2(ax, ay);
}

// ---------------- fused mean-pool + linear (batch is sorted) ----------------
__global__ __launch_bounds__(256) void k_pool_linear(const float* __restrict__ h,
                                                     const int* __restrict__ batch,
                                                     const float* __restrict__ Wl,
                                                     const float* __restrict__ bl,
                                                     float* __restrict__ out) {
    __shared__ int sb[2];
    __shared__ float4 sacc[256];
    __shared__ float xr[CH];
    __shared__ float po[4][OUT_CH];
    int g = blockIdx.x;
    int tid = threadIdx.x;
    if (tid < 2) {
        int target = g + tid;
        int lo = 0, hi = N_NODES;
        while (lo < hi) {
            int mid = (lo + hi) >> 1;
            if (batch[mid] < target) lo = mid + 1; else hi = mid;
        }
        sb[tid] = lo;
    }
    __syncthreads();
    int lo = sb[0], hi = sb[1];
    int q = tid & 31;   // channel quad
    int r = tid >> 5;   // row phase 0..7
    const float4* h4 = (const float4*)h;
    float4 acc = make_float4(0.f, 0.f, 0.f, 0.f);
    for (int i = lo + r; i < hi; i += 8) {
        float4 v = h4[(size_t)i * 32 + q];
        acc.x += v.x; acc.y += v.y; acc.z += v.z; acc.w += v.w;
    }
    sacc[tid] = acc;
    __syncthreads();
    if (r == 0) {
        #pragma unroll
        for (int p = 1; p < 8; ++p) {
            float4 t = sacc[q + p * 32];
            acc.x += t.x; acc.y += t.y; acc.z += t.z; acc.w += t.w;
        }
        float inv = 1.f / (float)((hi - lo) > 0 ? (hi - lo) : 1);
        xr[q * 4 + 0] = acc.x * inv;
        xr[q * 4 + 1] = acc.y * inv;
        xr[q * 4 + 2] = acc.z * inv;
        xr[q * 4 + 3] = acc.w * inv;
    }
    __syncthreads();
    int c = tid & 63;
    int kh = tid >> 6;
    float o = 0.f;
    #pragma unroll 8
    for (int k = kh * 32; k < kh * 32 + 32; ++k) o += xr[k] * Wl[k * OUT_CH + c];
    po[kh][c] = o;
    __syncthreads();
    if (tid < OUT_CH) {
        float v = bl[tid] + po[0][tid] + po[1][tid] + po[2][tid] + po[3][tid];
        out[g * OUT_CH + tid] = v;
    }
}

extern "C" void kernel_launch(void* const* d_in, const int* in_sizes, int n_in,
                              void* d_out, int out_size, void* d_ws, size_t ws_size,
                              hipStream_t stream) {
    const float* x    = (const float*)d_in[0];
    const float* W1   = (const float*)d_in[1];
    const float* b1   = (const float*)d_in[2];
    const float* W2   = (const float*)d_in[3];
    const float* b2   = (const float*)d_in[4];
    const float* Wlin = (const float*)d_in[5];
    const float* blin = (const float*)d_in[6];
    const int* ei     = (const int*)d_in[7];
    const int* batch  = (const int*)d_in[8];
    const int* esrc = ei;
    const int* edst = ei + N_EDGES;
    float* out = (float*)d_out;

    char* w = (char*)d_ws;
    size_t o = 0;
    float* hA            = (float*)(w + o);          o += (size_t)N_NODES * CH * 4;      // fp32 agg2 out
    unsigned short* hb   = (unsigned short*)(w + o); o += (size_t)N_NODES * CH * 2;      // bf16 prescaled gemm out
    uint32* habf         = (uint32*)(w + o);         o += (size_t)N_NODES * 64 * 4;      // bf16 agg1 out
    unsigned short* W1t  = (unsigned short*)(w + o); o += 16384 * 2;
    unsigned short* W2t  = (unsigned short*)(w + o); o += 16384 * 2;
    int* srcs            = (int*)(w + o);            o += (size_t)N_NODES * DSTRIDE * 4; // padded buckets
    int* cur             = (int*)(w + o);            o += 200704;
    (void)ws_size; (void)in_sizes; (void)n_in; (void)out_size;

    dim3 b256(256);
    k_prep<<<dim3(196), b256, 0, stream>>>(W1, W2, W1t, W2t, cur);
    k_fill_pad<<<dim3((N_EDGES / 4 + 255) / 256), b256, 0, stream>>>(
        (const int4*)esrc, (const int4*)edst, cur, srcs);

    dim3 gG((N_NODES + 127) / 128);   // 391 blocks
    dim3 gA(N_NODES / 4);             // 12500 blocks, one wave64 per node
    k_gemm<true><<<gG, b256, 0, stream>>>(x, W1t, cur, hb);
    k_agg<true><<<gA, b256, 0, stream>>>((const uint32*)hb, cur, srcs, b1, habf);
    k_gemm<false><<<gG, b256, 0, stream>>>(habf, W2t, cur, hb);
    k_agg<false><<<gA, b256, 0, stream>>>((const uint32*)hb, cur, srcs, b2, hA);
    k_pool_linear<<<dim3(NUM_GRAPHS), b256, 0, stream>>>(hA, batch, Wlin, blin, out);
}